// Round 19
// baseline (661.691 us; speedup 1.0000x reference)
//
#include <hip/hip_runtime.h>
#include <hip/hip_bf16.h>
#include <cstdint>
#include <cstddef>

// Problem constants (B=4, T=2048, DIM=2048, S=4, DFF=8192)
#define DIM   2048
#define DFF   8192
#define NROWS 8192   // B*T
#define NFOLD 24     // 4 (pre) + 4 (post) + 16 (res)

typedef float f32x4 __attribute__((ext_vector_type(4)));
typedef float f32x16 __attribute__((ext_vector_type(16)));
typedef __bf16 bf16x8 __attribute__((ext_vector_type(8)));

__device__ __forceinline__ float sigmoidf_(float v) { return 1.0f / (1.0f + expf(-v)); }

__device__ __forceinline__ unsigned short f2bf(float v) {
    union { __hip_bfloat16 h; unsigned short u; } cv;
    cv.h = __float2bfloat16(v);
    return cv.u;
}

__device__ __forceinline__ void async_copy16(const void* g, void* l) {
    __builtin_amdgcn_global_load_lds((const __attribute__((address_space(1))) void*)g,
                                     (__attribute__((address_space(3))) void*)l, 16, 0, 0);
}

// Raw workgroup barrier WITHOUT waitcnt drain (keeps global_load_lds in flight).
__device__ __forceinline__ void wg_barrier() {
    asm volatile("" ::: "memory");
    __builtin_amdgcn_s_barrier();
    asm volatile("" ::: "memory");
}

#define VM(n)  asm volatile("s_waitcnt vmcnt(" #n ")" ::: "memory")
#define LGKM0  asm volatile("s_waitcnt lgkmcnt(0)" ::: "memory")
// ROUND 19: MFMA-shape A/B on the winning r17 2-barrier schedule.
// GEMM1 uses v_mfma_f32_32x32x16_bf16 (2382 TF ubench vs 2075 for 16x16 —
// 15% fewer matrix-pipe cycles/FLOP; fragment-read count identical at 24
// b128/wave/tile so the LDS port load and sync skeleton are unchanged).
// GEMM2 keeps the r17 16x16 kernel as the in-probe control (267us).

// ---------------------------------------------------------------------------
// Fold phi weights: Wfold[r][d] = sum_{j<4} src[r][j*DIM + d], r in [0,24)
// ---------------------------------------------------------------------------
__global__ __launch_bounds__(256) void fold_kernel(const float* __restrict__ pre_w,
                                                   const float* __restrict__ post_w,
                                                   const float* __restrict__ res_w,
                                                   float* __restrict__ Wfold) {
    int idx = blockIdx.x * 256 + threadIdx.x;
    if (idx >= NFOLD * DIM) return;
    int r = idx >> 11;          // /DIM
    int d = idx & (DIM - 1);
    const float* src;
    if (r < 4)      src = pre_w  + (size_t)r * (4 * DIM);
    else if (r < 8) src = post_w + (size_t)(r - 4) * (4 * DIM);
    else            src = res_w  + (size_t)(r - 8) * (4 * DIM);
    Wfold[idx] = src[d] + src[DIM + d] + src[2 * DIM + d] + src[3 * DIM + d];
}

// ---------------------------------------------------------------------------
// Transpose f32 [R][C] -> bf16 [C][R]. Vectorized (float4 + ushort4).
// ---------------------------------------------------------------------------
__global__ __launch_bounds__(256) void transpose_to_bf16(const float* __restrict__ in,
                                                         __hip_bfloat16* __restrict__ out,
                                                         int R, int C) {
    __shared__ float tile[32][33];
    const int bx = blockIdx.x, by = blockIdx.y;
    const int t = threadIdx.x;
    const int lr = t >> 3;          // 0..31
    const int lc = (t & 7) * 4;     // 0,4,...,28

    float4 v = *(const float4*)(in + (size_t)(by * 32 + lr) * C + bx * 32 + lc);
    tile[lr][lc + 0] = v.x; tile[lr][lc + 1] = v.y;
    tile[lr][lc + 2] = v.z; tile[lr][lc + 3] = v.w;
    __syncthreads();

    ushort4 u;
    u.x = f2bf(tile[lc + 0][lr]); u.y = f2bf(tile[lc + 1][lr]);
    u.z = f2bf(tile[lc + 2][lr]); u.w = f2bf(tile[lc + 3][lr]);
    *reinterpret_cast<ushort4*>(out + (size_t)(bx * 32 + lr) * R + by * 32 + lc) = u;
}

// ---------------------------------------------------------------------------
// Gating: wave-per-row, 8 rows per block (512 threads).
// ---------------------------------------------------------------------------
__global__ __launch_bounds__(512) void gating_kernel(
    const float* __restrict__ x, const float* __restrict__ Wfold,
    const float* __restrict__ phi_pre_b, const float* __restrict__ phi_post_b,
    const float* __restrict__ phi_res_b,
    const float* __restrict__ alpha_pre, const float* __restrict__ alpha_post,
    const float* __restrict__ alpha_res,
    const float* __restrict__ b_pre, const float* __restrict__ b_post,
    const float* __restrict__ b_res,
    __hip_bfloat16* __restrict__ Abuf,
    float* __restrict__ g_res_arr, float* __restrict__ g_post_arr) {
    const int tid = threadIdx.x;
    const int lane = tid & 63, wave = tid >> 6;
    const int row = blockIdx.x * 8 + wave;

    const float4* x4 = (const float4*)x + (size_t)row * 512;
    const float4* w4 = (const float4*)Wfold;

    float4 xv[8];
#pragma unroll
    for (int j = 0; j < 8; j++) xv[j] = x4[j * 64 + lane];

    float p[25];
    p[24] = 0.f;
#pragma unroll
    for (int j = 0; j < 8; j++)
        p[24] += xv[j].x * xv[j].x + xv[j].y * xv[j].y + xv[j].z * xv[j].z + xv[j].w * xv[j].w;

    for (int r = 0; r < NFOLD; r++) {
        float acc = 0.f;
#pragma unroll
        for (int j = 0; j < 8; j++) {
            float4 wv = w4[r * 512 + j * 64 + lane];
            acc += xv[j].x * wv.x + xv[j].y * wv.y + xv[j].z * wv.z + xv[j].w * wv.w;
        }
        p[r] = acc;
    }

#pragma unroll
    for (int r = 0; r < 25; r++) {
        float v = p[r];
#pragma unroll
        for (int off = 1; off < 64; off <<= 1) v += __shfl_xor(v, off, 64);
        p[r] = v;
    }

    const float rms = rsqrtf(p[24] / (float)DIM + 1.1920928955078125e-07f);
    const float ap = alpha_pre[0], aq = alpha_post[0], ar = alpha_res[0];
    float gpre = 0.f, gpost = 0.f;
#pragma unroll
    for (int s = 0; s < 4; s++) {
        gpre  += sigmoidf_(ap * (rms * p[s]     + phi_pre_b[s])  + b_pre[s]);
        gpost += 2.0f * sigmoidf_(aq * (rms * p[4 + s] + phi_post_b[s]) + b_post[s]);
    }
    float Mm[4][4];
#pragma unroll
    for (int i = 0; i < 4; i++)
#pragma unroll
        for (int j = 0; j < 4; j++) {
            int k = i * 4 + j;
            Mm[i][j] = expf(ar * (rms * p[8 + k] + phi_res_b[k]) + b_res[k]);
        }
    for (int it = 0; it < 10; ++it) {
#pragma unroll
        for (int i = 0; i < 4; i++) {
            float rs = 1.0f / (Mm[i][0] + Mm[i][1] + Mm[i][2] + Mm[i][3]);
#pragma unroll
            for (int j = 0; j < 4; j++) Mm[i][j] *= rs;
        }
#pragma unroll
        for (int j = 0; j < 4; j++) {
            float cs = 1.0f / (Mm[0][j] + Mm[1][j] + Mm[2][j] + Mm[3][j]);
#pragma unroll
            for (int i = 0; i < 4; i++) Mm[i][j] *= cs;
        }
    }
    float gres = 0.f;
#pragma unroll
    for (int i = 0; i < 4; i++)
#pragma unroll
        for (int j = 0; j < 4; j++) gres += Mm[i][j];

    __hip_bfloat16* arow = Abuf + (size_t)row * DIM;
#pragma unroll
    for (int j = 0; j < 8; j++) {
        ushort4 u;
        u.x = f2bf(xv[j].x * gpre); u.y = f2bf(xv[j].y * gpre);
        u.z = f2bf(xv[j].z * gpre); u.w = f2bf(xv[j].w * gpre);
        *reinterpret_cast<ushort4*>(arow + (j * 64 + lane) * 4) = u;
    }
    if (lane == 0) {
        g_res_arr[row]  = gres;
        g_post_arr[row] = gpost;
    }
}

// Shared staging macros (identical LDS layout for both GEMM variants):
// Unit region [128 rows][128 B], byte col ^ ((row&7)<<4); global_load_lds
// writes linearly, inverse XOR pre-applied on the per-lane global source.
#define STG_A(t_, h_)                                                             \
    if ((t_) < nk) {                                                              \
        char* l_ = ldsA + (((t_) & 1) * 32768) + (h_) * 16384 + wave * 1024;      \
        async_copy16(Ab + aOff[0][h_] + (size_t)(t_) * 128, l_);                  \
        async_copy16(Ab + aOff[1][h_] + (size_t)(t_) * 128, l_ + 8192);           \
    }
#define STG_B(t_, h_)                                                             \
    if ((t_) < nk) {                                                              \
        char* l_ = ldsB + (((t_) & 1) * 32768) + (h_) * 16384 + wave * 1024;      \
        async_copy16(Bb + bOff[0][h_] + (size_t)(t_) * 128, l_);                  \
        async_copy16(Bb + bOff[1][h_] + (size_t)(t_) * 128, l_ + 8192);           \
    }

#define STAGE_ADDR_SETUP                                                          \
    const uint32_t scb = (uint32_t)((((lane & 7) ^ ((lane >> 3) & 7))) << 4);     \
    const int lr_ = lane >> 3;                                                    \
    const size_t K2 = (size_t)K * 2;                                              \
    size_t aOff[2][2], bOff[2][2];                                                \
    _Pragma("unroll") for (int ii = 0; ii < 2; ++ii)                              \
    _Pragma("unroll") for (int h = 0; h < 2; ++h) {                               \
        int gA = m0 + wave * 8 + lr_ + ii * 128 + h * 64;                         \
        int gB = n0 + ((wave >> 2) + 2 * ii) * 64 + h * 32 + (wave & 3) * 8 + lr_;\
        aOff[ii][h] = (size_t)gA * K2 + scb;                                      \
        bOff[ii][h] = (size_t)gB * K2 + scb;                                      \
    }

// ===========================================================================
// VARIANT (GEMM1): 256x256, BK=64, r17 2-barrier schedule, 32x32x16 MFMA.
// Per wave: m-tiles 4 (32 rows), n-tiles 2 (32 cols), ks 4 (K=16 each).
// A-frag: row lane&31, k = ks*16+(lane>>5)*8 (one b128); same for B^T rows.
// C/D: col = lane&31, row = (reg&3)+8*(reg>>2)+4*(lane>>5)  [m74/m101].
//   Ph1: rd a(A0)[8]+b0[4]+b1[4]; stg A1,B1(t+1); BAR; LGKM0; 16 MFMA
//   Ph2: rd a(A1)[8];             stg A0,B0(t+2); VM(4|0); BAR; LGKM0; 16 MFMA
// Sync/stage/vmcnt audits inherited verbatim from r17 (read counts per phase
// identical: 16/8).
// ===========================================================================
template <int NB>
__global__ __launch_bounds__(512, 2) void gemm256_w32(
    const __hip_bfloat16* __restrict__ A, const __hip_bfloat16* __restrict__ Bt,
    int M, int N, int K, const float* __restrict__ bias,
    __hip_bfloat16* __restrict__ outh) {
    __shared__ __align__(16) char ldsA[65536];
    __shared__ __align__(16) char ldsB[65536];

    const int wg = blockIdx.x;
    const int xcd = wg & 7;
    const int i = wg >> 3;
    const int nt = xcd * NB + (i % NB);
    const int mt = i / NB;
    const int m0 = mt * 256;
    const int n0 = nt * 256;

    const int tid = threadIdx.x;
    const int lane = tid & 63;
    const int wave = tid >> 6;            // 0..7
    const int wr = wave >> 2;             // 0..1 (M)
    const int wc = wave & 3;              // 0..3 (N)
    const int lane31 = lane & 31;
    const int lhalf = lane >> 5;          // 0..1
    const int x7 = lane31 & 7;

    // ds_read addressing: slot s = ks*2 + lhalf, byte = (s ^ (row&7))<<4
    uint32_t cb32[4];
#pragma unroll
    for (int ks = 0; ks < 4; ++ks)
        cb32[ks] = (uint32_t)(((ks * 2 + lhalf) ^ x7) << 4);
    const uint32_t bA0r = (uint32_t)((wr * 64 + lane31) * 128);        // m2=0
    const uint32_t bA1r = (uint32_t)((wr * 64 + 32 + lane31) * 128);   // m2=1
    const uint32_t bBr  = (uint32_t)((wc * 32 + lane31) * 128);

    STAGE_ADDR_SETUP
    const char* Ab = (const char*)A;
    const char* Bb = (const char*)Bt;

    f32x16 acc[4][2];
#pragma unroll
    for (int m = 0; m < 4; ++m)
#pragma unroll
        for (int n = 0; n < 2; ++n)
#pragma unroll
            for (int j = 0; j < 16; ++j) acc[m][n][j] = 0.f;

    const int nk = K / 64;

    // Prologue: tile0 {A0,B0,B1,A1} + {A0,B0}(1); VM(4).
    STG_A(0, 0); STG_B(0, 0); STG_B(0, 1); STG_A(0, 1);
    STG_A(1, 0); STG_B(1, 0);
    VM(4);
    wg_barrier();

    bf16x8 fa[2][4], fa2[2][4], fb0[4], fb1[4];

    for (int kt = 0; kt < nk; ++kt) {
        const int c = kt & 1;
        const char* Ac = ldsA + c * 32768;
        const char* Bc = ldsB + c * 32768;
        // ---- Ph1: rd A0 frags + b0 + b1; stg A1,B1(t+1)
#pragma unroll
        for (int ks = 0; ks < 4; ++ks) {
            fa[0][ks] = *(const bf16x8*)(Ac + bA0r + cb32[ks]);
            fa[1][ks] = *(const bf16x8*)(Ac + bA1r + cb32[ks]);
            fb0[ks]   = *(const bf16x8*)(Bc + bBr + cb32[ks]);
            fb1[ks]   = *(const bf16x8*)(Bc + 16384 + bBr + cb32[ks]);
        }
        STG_A(kt + 1, 1)
        STG_B(kt + 1, 1)
        wg_barrier();
        LGKM0;
        __builtin_amdgcn_s_setprio(1);
#pragma unroll
        for (int m2 = 0; m2 < 2; ++m2)
#pragma unroll
            for (int ks = 0; ks < 4; ++ks) {
                acc[m2][0] = __builtin_amdgcn_mfma_f32_32x32x16_bf16(
                    fa[m2][ks], fb0[ks], acc[m2][0], 0, 0, 0);
                acc[m2][1] = __builtin_amdgcn_mfma_f32_32x32x16_bf16(
                    fa[m2][ks], fb1[ks], acc[m2][1], 0, 0, 0);
            }
        __builtin_amdgcn_s_setprio(0);
        // ---- Ph2: rd A1 frags; stg A0,B0(t+2); VM(4|0)
#pragma unroll
        for (int ks = 0; ks < 4; ++ks) {
            fa2[0][ks] = *(const bf16x8*)(Ac + 16384 + bA0r + cb32[ks]);
            fa2[1][ks] = *(const bf16x8*)(Ac + 16384 + bA1r + cb32[ks]);
        }
        STG_A(kt + 2, 0)
        STG_B(kt + 2, 0)
        if (kt + 2 < nk) { VM(4); } else { VM(0); }
        wg_barrier();
        LGKM0;
        __builtin_amdgcn_s_setprio(1);
#pragma unroll
        for (int m2 = 0; m2 < 2; ++m2)
#pragma unroll
            for (int ks = 0; ks < 4; ++ks) {
                acc[2 + m2][0] = __builtin_amdgcn_mfma_f32_32x32x16_bf16(
                    fa2[m2][ks], fb0[ks], acc[2 + m2][0], 0, 0, 0);
                acc[2 + m2][1] = __builtin_amdgcn_mfma_f32_32x32x16_bf16(
                    fa2[m2][ks], fb1[ks], acc[2 + m2][1], 0, 0, 0);
            }
        __builtin_amdgcn_s_setprio(0);
    }

    // Epilogue: rows = m0 + wr*128 + (mi>>1)*64 + (mi&1)*32 + (reg&3) +
    //                  8*(reg>>2) + 4*lhalf; cols = n0 + wc*64 + ni*32 + lane31
#pragma unroll
    for (int mi = 0; mi < 4; ++mi) {
#pragma unroll
        for (int ni = 0; ni < 2; ++ni) {
            const int col = n0 + wc * 64 + ni * 32 + lane31;
            const float bc = bias[col];
            const int rb = m0 + wr * 128 + (mi >> 1) * 64 + (mi & 1) * 32 + 4 * lhalf;
#pragma unroll
            for (int reg = 0; reg < 16; ++reg) {
                const int row = rb + (reg & 3) + 8 * (reg >> 2);
                float v = acc[mi][ni][reg] + bc;
                float u = 1.5957691216057308f * (v + 0.044715f * v * v * v);
                float s = 1.0f / (1.0f + __expf(-u));
                outh[(size_t)row * N + col] = __float2bfloat16(v * s);
            }
        }
    }
}

// ===========================================================================
// CONTROL (GEMM2): r17 16x16x32 kernel verbatim (2-barrier, LGKM0 post-bar).
// ===========================================================================
#define RD_A(DST, REG)                                                            \
    _Pragma("unroll") for (int m = 0; m < 4; ++m) {                               \
        DST[m][0] = *(const bf16x8*)((REG) + baseA + m * 2048 + cb0);             \
        DST[m][1] = *(const bf16x8*)((REG) + baseA + m * 2048 + cb1);             \
    }
#define RD_B(DST, REG)                                                            \
    _Pragma("unroll") for (int n = 0; n < 2; ++n) {                               \
        DST[n][0] = *(const bf16x8*)((REG) + baseB + n * 2048 + cb0);             \
        DST[n][1] = *(const bf16x8*)((REG) + baseB + n * 2048 + cb1);             \
    }

#define MQ(AF, BF, MO, NO)                                                        \
    __builtin_amdgcn_s_setprio(1);                                                \
    _Pragma("unroll") for (int m = 0; m < 4; ++m)                                 \
    _Pragma("unroll") for (int n = 0; n < 2; ++n) {                               \
        acc[(MO) + m][(NO) + n] = __builtin_amdgcn_mfma_f32_16x16x32_bf16(        \
            AF[m][0], BF[n][0], acc[(MO) + m][(NO) + n], 0, 0, 0);                \
        acc[(MO) + m][(NO) + n] = __builtin_amdgcn_mfma_f32_16x16x32_bf16(        \
            AF[m][1], BF[n][1], acc[(MO) + m][(NO) + n], 0, 0, 0);                \
    }                                                                             \
    __builtin_amdgcn_s_setprio(0);

template <int MODE, int NB>
__global__ __launch_bounds__(512, 2) void gemm256(
    const __hip_bfloat16* __restrict__ A, const __hip_bfloat16* __restrict__ Bt,
    int M, int N, int K, const float* __restrict__ bias,
    __hip_bfloat16* __restrict__ outh, float* __restrict__ outf,
    const float* __restrict__ x, const float* __restrict__ g_res,
    const float* __restrict__ g_post) {
    __shared__ __align__(16) char ldsA[65536];
    __shared__ __align__(16) char ldsB[65536];

    const int wg = blockIdx.x;
    const int xcd = wg & 7;
    const int i = wg >> 3;
    const int nt = xcd * NB + (i % NB);
    const int mt = i / NB;
    const int m0 = mt * 256;
    const int n0 = nt * 256;

    const int tid = threadIdx.x;
    const int lane = tid & 63;
    const int wave = tid >> 6;            // 0..7
    const int wr = wave >> 2;             // 0..1 (M)
    const int wc = wave & 3;              // 0..3 (N)
    const int q = lane >> 4;              // 0..3
    const int rr = lane & 7;

    const uint32_t cb0 = (uint32_t)((q ^ rr) << 4);         // ks=0
    const uint32_t cb1 = (uint32_t)(((4 + q) ^ rr) << 4);   // ks=1
    const uint32_t baseA = (uint32_t)((wr * 64 + (lane & 15)) * 128);
    const uint32_t baseB = (uint32_t)((wc * 32 + (lane & 15)) * 128);

    STAGE_ADDR_SETUP
    const char* Ab = (const char*)A;
    const char* Bb = (const char*)Bt;

    f32x4 acc[8][4];
#pragma unroll
    for (int m = 0; m < 8; ++m)
#pragma unroll
        for (int n = 0; n < 4; ++n) acc[m][n] = (f32x4){0.f, 0.f, 0.f, 0.f};

    const int nk = K / 64;

    STG_A(0, 0); STG_B(0, 0); STG_B(0, 1); STG_A(0, 1);
    STG_A(1, 0); STG_B(1, 0);
    VM(4);
    wg_barrier();

    bf16x8 a0[4][2], a1[4][2];
    bf16x8 b0[2][2], b1[2][2];

    for (int kt = 0; kt < nk; ++kt) {
        const int c = kt & 1;
        const char* Ac = ldsA + c * 32768;
        const char* Bc = ldsB + c * 32768;
        // ---- Ph1
        RD_A(a0, Ac)
        RD_B(b0, Bc)
        RD_B(b1, Bc + 16384)
        STG_A(kt + 1, 1)
        STG_B(kt + 1, 1)
        wg_barrier();
        LGKM0;
        MQ(a0, b0, 0, 0)
        MQ(a0, b1, 0, 2)
        // ---- Ph2
        RD_A(a1, Ac + 16384)
        STG_A(kt + 2, 0)
        STG_B(kt + 2, 0)
        if (kt + 2 < nk) { VM(4); } else { VM(0); }
        wg_barrier();
        LGKM0;
        MQ(a1, b0, 4, 0)
        MQ(a1, b1, 4, 2)
    }

#pragma unroll
    for (int mi = 0; mi < 8; ++mi) {
#pragma unroll
        for (int ni = 0; ni < 4; ++ni) {
            const int col = n0 + wc * 64 + (ni >> 1) * 32 + (ni & 1) * 16 + (lane & 15);
            const float bc = bias[col];
#pragma unroll
            for (int j = 0; j < 4; ++j) {
                const int row = m0 + wr * 128 + (mi >> 2) * 64 + (mi & 3) * 16 + q * 4 + j;
                float v = acc[mi][ni][j] + bc;
                if (MODE == 1) {
                    float u = 1.5957691216057308f * (v + 0.044715f * v * v * v);
                    float s = 1.0f / (1.0f + __expf(-u));
                    outh[(size_t)row * N + col] = __float2bfloat16(v * s);
                } else {
                    outf[(size_t)row * N + col] =
                        x[(size_t)row * N + col] * g_res[row] + v * g_post[row];
                }
            }
        }
    }
}

// ---------------------------------------------------------------------------
// Workspace layout (~235.2 MB): W1T, W2T, Abuf, Hbuf, Wfold, gres, gpost
// ---------------------------------------------------------------------------
extern "C" void kernel_launch(void* const* d_in, const int* in_sizes, int n_in,
                              void* d_out, int out_size, void* d_ws, size_t ws_size,
                              hipStream_t stream) {
    const float* x          = (const float*)d_in[0];
    const float* phi_pre_w  = (const float*)d_in[1];
    const float* phi_pre_b  = (const float*)d_in[2];
    const float* phi_post_w = (const float*)d_in[3];
    const float* phi_post_b = (const float*)d_in[4];
    const float* phi_res_w  = (const float*)d_in[5];
    const float* phi_res_b  = (const float*)d_in[6];
    const float* alpha_pre  = (const float*)d_in[7];
    const float* alpha_post = (const float*)d_in[8];
    const float* alpha_res  = (const float*)d_in[9];
    const float* b_pre      = (const float*)d_in[10];
    const float* b_post     = (const float*)d_in[11];
    const float* b_res      = (const float*)d_in[12];
    const float* W1         = (const float*)d_in[13];
    const float* b1         = (const float*)d_in[14];
    const float* W2         = (const float*)d_in[15];
    const float* b2         = (const float*)d_in[16];
    float* out = (float*)d_out;

    char* ws = (char*)d_ws;
    __hip_bfloat16* W1T  = (__hip_bfloat16*)ws;                      // [DFF][DIM]
    __hip_bfloat16* W2T  = W1T + (size_t)DFF * DIM;                  // [DIM][DFF]
    __hip_bfloat16* Abuf = W2T + (size_t)DIM * DFF;                  // [NROWS][DIM]
    __hip_bfloat16* Hbuf = Abuf + (size_t)NROWS * DIM;               // [NROWS][DFF]
    float* Wfold = (float*)(Hbuf + (size_t)NROWS * DFF);             // [24][DIM]
    float* gres  = Wfold + NFOLD * DIM;
    float* gpost = gres + NROWS;

    fold_kernel<<<(NFOLD * DIM + 255) / 256, 256, 0, stream>>>(phi_pre_w, phi_post_w,
                                                               phi_res_w, Wfold);
    transpose_to_bf16<<<dim3(DFF / 32, DIM / 32), 256, 0, stream>>>(W1, W1T, DIM, DFF);
    transpose_to_bf16<<<dim3(DIM / 32, DFF / 32), 256, 0, stream>>>(W2, W2T, DFF, DIM);
    gating_kernel<<<NROWS / 8, 512, 0, stream>>>(x, Wfold, phi_pre_b, phi_post_b, phi_res_b,
                                                 alpha_pre, alpha_post, alpha_res,
                                                 b_pre, b_post, b_res, Abuf, gres, gpost);
    // GEMM1 (VARIANT: 32x32x16 MFMA): grid 32x32=1024, NB=4
    gemm256_w32<4><<<1024, 512, 0, stream>>>(
        Abuf, W1T, NROWS, DFF, DIM, b1, Hbuf);
    // GEMM2 (CONTROL: r17 16x16x32): grid 32x8=256, NB=1
    gemm256<2, 1><<<256, 512, 0, stream>>>(
        Hbuf, W2T, NROWS, DIM, DFF, b2, nullptr, out, x, gres, gpost);
}

// Round 20
// 629.214 us; speedup vs baseline: 1.0516x; 1.0516x over previous
//
#include <hip/hip_runtime.h>
#include <hip/hip_bf16.h>
#include <cstdint>
#include <cstddef>

// Problem constants (B=4, T=2048, DIM=2048, S=4, DFF=8192)
#define DIM   2048
#define DFF   8192
#define NROWS 8192   // B*T
#define NFOLD 24     // 4 (pre) + 4 (post) + 16 (res)

typedef float f32x4 __attribute__((ext_vector_type(4)));
typedef __bf16 bf16x8 __attribute__((ext_vector_type(8)));

__device__ __forceinline__ float sigmoidf_(float v) { return 1.0f / (1.0f + expf(-v)); }

__device__ __forceinline__ unsigned short f2bf(float v) {
    union { __hip_bfloat16 h; unsigned short u; } cv;
    cv.h = __float2bfloat16(v);
    return cv.u;
}

__device__ __forceinline__ void async_copy16(const void* g, void* l) {
    __builtin_amdgcn_global_load_lds((const __attribute__((address_space(1))) void*)g,
                                     (__attribute__((address_space(3))) void*)l, 16, 0, 0);
}

// Raw workgroup barrier WITHOUT waitcnt drain (keeps global_load_lds in flight).
__device__ __forceinline__ void wg_barrier() {
    asm volatile("" ::: "memory");
    __builtin_amdgcn_s_barrier();
    asm volatile("" ::: "memory");
}

#define VM(n)  asm volatile("s_waitcnt vmcnt(" #n ")" ::: "memory")
#define LGKM0  asm volatile("s_waitcnt lgkmcnt(0)" ::: "memory")
// ROUND 20: revert to the best-measured configuration (r17/r18): both GEMMs
// on the 16x16x32 2-barrier unit-ring schedule. r19's 32x32x16 A/B was
// rejected per pre-commit (288us vs 266 control; 2.5e7 bank conflicts from
// the 32-row fragment pattern's 4-way slot aliasing — no conflict-free
// swizzle exists with 8 slots/row). 1-barrier/tile proven impossible (any
// single-barrier body leaves a stage-issue/read pair with zero barriers
// between them). This config: 630us total, GEMMs 266-267us, MfmaUtil 47%.

// ---------------------------------------------------------------------------
// Fold phi weights: Wfold[r][d] = sum_{j<4} src[r][j*DIM + d], r in [0,24)
// ---------------------------------------------------------------------------
__global__ __launch_bounds__(256) void fold_kernel(const float* __restrict__ pre_w,
                                                   const float* __restrict__ post_w,
                                                   const float* __restrict__ res_w,
                                                   float* __restrict__ Wfold) {
    int idx = blockIdx.x * 256 + threadIdx.x;
    if (idx >= NFOLD * DIM) return;
    int r = idx >> 11;          // /DIM
    int d = idx & (DIM - 1);
    const float* src;
    if (r < 4)      src = pre_w  + (size_t)r * (4 * DIM);
    else if (r < 8) src = post_w + (size_t)(r - 4) * (4 * DIM);
    else            src = res_w  + (size_t)(r - 8) * (4 * DIM);
    Wfold[idx] = src[d] + src[DIM + d] + src[2 * DIM + d] + src[3 * DIM + d];
}

// ---------------------------------------------------------------------------
// Transpose f32 [R][C] -> bf16 [C][R]. Vectorized (float4 + ushort4).
// ---------------------------------------------------------------------------
__global__ __launch_bounds__(256) void transpose_to_bf16(const float* __restrict__ in,
                                                         __hip_bfloat16* __restrict__ out,
                                                         int R, int C) {
    __shared__ float tile[32][33];
    const int bx = blockIdx.x, by = blockIdx.y;
    const int t = threadIdx.x;
    const int lr = t >> 3;          // 0..31
    const int lc = (t & 7) * 4;     // 0,4,...,28

    float4 v = *(const float4*)(in + (size_t)(by * 32 + lr) * C + bx * 32 + lc);
    tile[lr][lc + 0] = v.x; tile[lr][lc + 1] = v.y;
    tile[lr][lc + 2] = v.z; tile[lr][lc + 3] = v.w;
    __syncthreads();

    ushort4 u;
    u.x = f2bf(tile[lc + 0][lr]); u.y = f2bf(tile[lc + 1][lr]);
    u.z = f2bf(tile[lc + 2][lr]); u.w = f2bf(tile[lc + 3][lr]);
    *reinterpret_cast<ushort4*>(out + (size_t)(bx * 32 + lr) * R + by * 32 + lc) = u;
}

// ---------------------------------------------------------------------------
// Gating: wave-per-row, 8 rows per block (512 threads).
// ---------------------------------------------------------------------------
__global__ __launch_bounds__(512) void gating_kernel(
    const float* __restrict__ x, const float* __restrict__ Wfold,
    const float* __restrict__ phi_pre_b, const float* __restrict__ phi_post_b,
    const float* __restrict__ phi_res_b,
    const float* __restrict__ alpha_pre, const float* __restrict__ alpha_post,
    const float* __restrict__ alpha_res,
    const float* __restrict__ b_pre, const float* __restrict__ b_post,
    const float* __restrict__ b_res,
    __hip_bfloat16* __restrict__ Abuf,
    float* __restrict__ g_res_arr, float* __restrict__ g_post_arr) {
    const int tid = threadIdx.x;
    const int lane = tid & 63, wave = tid >> 6;
    const int row = blockIdx.x * 8 + wave;

    const float4* x4 = (const float4*)x + (size_t)row * 512;
    const float4* w4 = (const float4*)Wfold;

    float4 xv[8];
#pragma unroll
    for (int j = 0; j < 8; j++) xv[j] = x4[j * 64 + lane];

    float p[25];
    p[24] = 0.f;
#pragma unroll
    for (int j = 0; j < 8; j++)
        p[24] += xv[j].x * xv[j].x + xv[j].y * xv[j].y + xv[j].z * xv[j].z + xv[j].w * xv[j].w;

    for (int r = 0; r < NFOLD; r++) {
        float acc = 0.f;
#pragma unroll
        for (int j = 0; j < 8; j++) {
            float4 wv = w4[r * 512 + j * 64 + lane];
            acc += xv[j].x * wv.x + xv[j].y * wv.y + xv[j].z * wv.z + xv[j].w * wv.w;
        }
        p[r] = acc;
    }

#pragma unroll
    for (int r = 0; r < 25; r++) {
        float v = p[r];
#pragma unroll
        for (int off = 1; off < 64; off <<= 1) v += __shfl_xor(v, off, 64);
        p[r] = v;
    }

    const float rms = rsqrtf(p[24] / (float)DIM + 1.1920928955078125e-07f);
    const float ap = alpha_pre[0], aq = alpha_post[0], ar = alpha_res[0];
    float gpre = 0.f, gpost = 0.f;
#pragma unroll
    for (int s = 0; s < 4; s++) {
        gpre  += sigmoidf_(ap * (rms * p[s]     + phi_pre_b[s])  + b_pre[s]);
        gpost += 2.0f * sigmoidf_(aq * (rms * p[4 + s] + phi_post_b[s]) + b_post[s]);
    }
    float Mm[4][4];
#pragma unroll
    for (int i = 0; i < 4; i++)
#pragma unroll
        for (int j = 0; j < 4; j++) {
            int k = i * 4 + j;
            Mm[i][j] = expf(ar * (rms * p[8 + k] + phi_res_b[k]) + b_res[k]);
        }
    for (int it = 0; it < 10; ++it) {
#pragma unroll
        for (int i = 0; i < 4; i++) {
            float rs = 1.0f / (Mm[i][0] + Mm[i][1] + Mm[i][2] + Mm[i][3]);
#pragma unroll
            for (int j = 0; j < 4; j++) Mm[i][j] *= rs;
        }
#pragma unroll
        for (int j = 0; j < 4; j++) {
            float cs = 1.0f / (Mm[0][j] + Mm[1][j] + Mm[2][j] + Mm[3][j]);
#pragma unroll
            for (int i = 0; i < 4; i++) Mm[i][j] *= cs;
        }
    }
    float gres = 0.f;
#pragma unroll
    for (int i = 0; i < 4; i++)
#pragma unroll
        for (int j = 0; j < 4; j++) gres += Mm[i][j];

    __hip_bfloat16* arow = Abuf + (size_t)row * DIM;
#pragma unroll
    for (int j = 0; j < 8; j++) {
        ushort4 u;
        u.x = f2bf(xv[j].x * gpre); u.y = f2bf(xv[j].y * gpre);
        u.z = f2bf(xv[j].z * gpre); u.w = f2bf(xv[j].w * gpre);
        *reinterpret_cast<ushort4*>(arow + (j * 64 + lane) * 4) = u;
    }
    if (lane == 0) {
        g_res_arr[row]  = gres;
        g_post_arr[row] = gpost;
    }
}

// ---------------------------------------------------------------------------
// 256x256 bf16 GEMM — unit-ring, TWO barriers per K-tile (r17 winner).
//   C[M][N] = A[M][K] @ Bt[N][K]^T; 8 waves (2M x 4N); per-wave out 128x64;
//   BK=64; LDS 128 KiB = 2 parities x {A0,A1,B0,B1} 16 KB units.
// Units: A0: rows {0-63,128-191} [a0] | A1: rows {64-127,192-255} [a1]
//        B0: cols {0-31,64-95,128-159,192-223} [b0] | B1: +32 [b1]
// Unit region [128 rows][128 B], byte col ^ ((row&7)<<4); global_load_lds
// writes linearly, inverse XOR pre-applied on the per-lane global source.
//
// Phase = { rd; stg; [VM]; BAR; LGKM0; 32 MFMA }
//   Ph1: rd a0,b0,b1(t)[16]; stg A1(t+1),B1(t+1)
//   Ph2: rd a1(t)[8];        stg A0(t+2),B0(t+2); VM(4|0)
// WAR: LGKM0 < MFMA < next BAR (r16/r17-validated). vmcnt FIFO: steady
// entering Ph1(t): {A0,B0}(t+1)[4]; Ph1 +4 -> 8; Ph2 +4 -> 12; VM(4) keeps
// {A0,B0}(t+2), drains tile t+1. Prologue: t0{A0,B0,B1,A1}+{A0,B0}(1);
// VM(4). Tail: VM(0), stage macros self-guard.
// ---------------------------------------------------------------------------
#define RD_A(DST, REG)                                                            \
    _Pragma("unroll") for (int m = 0; m < 4; ++m) {                               \
        DST[m][0] = *(const bf16x8*)((REG) + baseA + m * 2048 + cb0);             \
        DST[m][1] = *(const bf16x8*)((REG) + baseA + m * 2048 + cb1);             \
    }
#define RD_B(DST, REG)                                                            \
    _Pragma("unroll") for (int n = 0; n < 2; ++n) {                               \
        DST[n][0] = *(const bf16x8*)((REG) + baseB + n * 2048 + cb0);             \
        DST[n][1] = *(const bf16x8*)((REG) + baseB + n * 2048 + cb1);             \
    }

#define MQ(AF, BF, MO, NO)                                                        \
    __builtin_amdgcn_s_setprio(1);                                                \
    _Pragma("unroll") for (int m = 0; m < 4; ++m)                                 \
    _Pragma("unroll") for (int n = 0; n < 2; ++n) {                               \
        acc[(MO) + m][(NO) + n] = __builtin_amdgcn_mfma_f32_16x16x32_bf16(        \
            AF[m][0], BF[n][0], acc[(MO) + m][(NO) + n], 0, 0, 0);                \
        acc[(MO) + m][(NO) + n] = __builtin_amdgcn_mfma_f32_16x16x32_bf16(        \
            AF[m][1], BF[n][1], acc[(MO) + m][(NO) + n], 0, 0, 0);                \
    }                                                                             \
    __builtin_amdgcn_s_setprio(0);

#define STG_A(t_, h_)                                                             \
    if ((t_) < nk) {                                                              \
        char* l_ = ldsA + (((t_) & 1) * 32768) + (h_) * 16384 + wave * 1024;      \
        async_copy16(Ab + aOff[0][h_] + (size_t)(t_) * 128, l_);                  \
        async_copy16(Ab + aOff[1][h_] + (size_t)(t_) * 128, l_ + 8192);           \
    }
#define STG_B(t_, h_)                                                             \
    if ((t_) < nk) {                                                              \
        char* l_ = ldsB + (((t_) & 1) * 32768) + (h_) * 16384 + wave * 1024;      \
        async_copy16(Bb + bOff[0][h_] + (size_t)(t_) * 128, l_);                  \
        async_copy16(Bb + bOff[1][h_] + (size_t)(t_) * 128, l_ + 8192);           \
    }

template <int MODE, int NB>
__global__ __launch_bounds__(512, 2) void gemm256(
    const __hip_bfloat16* __restrict__ A, const __hip_bfloat16* __restrict__ Bt,
    int M, int N, int K, const float* __restrict__ bias,
    __hip_bfloat16* __restrict__ outh, float* __restrict__ outf,
    const float* __restrict__ x, const float* __restrict__ g_res,
    const float* __restrict__ g_post) {
    __shared__ __align__(16) char ldsA[65536];
    __shared__ __align__(16) char ldsB[65536];

    // XCD band swizzle: each XCD owns an NB-wide column band of tiles.
    const int wg = blockIdx.x;
    const int xcd = wg & 7;
    const int i = wg >> 3;
    const int nt = xcd * NB + (i % NB);
    const int mt = i / NB;
    const int m0 = mt * 256;
    const int n0 = nt * 256;

    const int tid = threadIdx.x;
    const int lane = tid & 63;
    const int wave = tid >> 6;            // 0..7
    const int wr = wave >> 2;             // 0..1 (M)
    const int wc = wave & 3;              // 0..3 (N)
    const int q = lane >> 4;              // 0..3
    const int rr = lane & 7;

    // ds_read addressing (bytes within a 16 KB unit region)
    const uint32_t cb0 = (uint32_t)((q ^ rr) << 4);         // ks=0
    const uint32_t cb1 = (uint32_t)(((4 + q) ^ rr) << 4);   // ks=1
    const uint32_t baseA = (uint32_t)((wr * 64 + (lane & 15)) * 128);
    const uint32_t baseB = (uint32_t)((wc * 32 + (lane & 15)) * 128);

    // staging source addressing
    const uint32_t scb = (uint32_t)((((lane & 7) ^ ((lane >> 3) & 7))) << 4);
    const int lr = lane >> 3;             // 0..7
    const size_t K2 = (size_t)K * 2;
    size_t aOff[2][2], bOff[2][2];
#pragma unroll
    for (int ii = 0; ii < 2; ++ii)
#pragma unroll
        for (int h = 0; h < 2; ++h) {
            int gA = m0 + wave * 8 + lr + ii * 128 + h * 64;
            int gB = n0 + ((wave >> 2) + 2 * ii) * 64 + h * 32 + (wave & 3) * 8 + lr;
            aOff[ii][h] = (size_t)gA * K2 + scb;
            bOff[ii][h] = (size_t)gB * K2 + scb;
        }
    const char* Ab = (const char*)A;
    const char* Bb = (const char*)Bt;

    f32x4 acc[8][4];
#pragma unroll
    for (int m = 0; m < 8; ++m)
#pragma unroll
        for (int n = 0; n < 4; ++n) acc[m][n] = (f32x4){0.f, 0.f, 0.f, 0.f};

    const int nk = K / 64;

    // Prologue: tile0 {A0,B0,B1,A1} + {A0,B0}(1); VM(4) = tile0 landed,
    // {A0,B0}(1) in flight (the loop invariant).
    STG_A(0, 0); STG_B(0, 0); STG_B(0, 1); STG_A(0, 1);
    STG_A(1, 0); STG_B(1, 0);
    VM(4);
    wg_barrier();

    bf16x8 a0[4][2], a1[4][2];
    bf16x8 b0[2][2], b1[2][2];

    for (int kt = 0; kt < nk; ++kt) {
        const int c = kt & 1;
        const char* Ac = ldsA + c * 32768;
        const char* Bc = ldsB + c * 32768;
        // ---- Ph1: rd a0,b0,b1(t); stg A1(t+1),B1(t+1)
        RD_A(a0, Ac)
        RD_B(b0, Bc)
        RD_B(b1, Bc + 16384)
        STG_A(kt + 1, 1)
        STG_B(kt + 1, 1)
        wg_barrier();
        LGKM0;
        MQ(a0, b0, 0, 0)
        MQ(a0, b1, 0, 2)
        // ---- Ph2: rd a1(t); stg A0(t+2),B0(t+2); VM(4|0)
        RD_A(a1, Ac + 16384)
        STG_A(kt + 2, 0)
        STG_B(kt + 2, 0)
        if (kt + 2 < nk) { VM(4); } else { VM(0); }
        wg_barrier();
        LGKM0;
        MQ(a1, b0, 4, 0)
        MQ(a1, b1, 4, 2)
    }

    // Epilogue. Row/col mapping follows the interleaved unit layout:
    //   rows:  m0 + wr*128 + (mi>>2)*64 + (mi&3)*16 + q*4 + j
    //   cols:  n0 + wc*64  + (ni>>1)*32 + (ni&1)*16 + (lane&15)
#pragma unroll
    for (int mi = 0; mi < 8; ++mi) {
#pragma unroll
        for (int ni = 0; ni < 4; ++ni) {
            const int col = n0 + wc * 64 + (ni >> 1) * 32 + (ni & 1) * 16 + (lane & 15);
            const float bc = bias[col];
#pragma unroll
            for (int j = 0; j < 4; ++j) {
                const int row = m0 + wr * 128 + (mi >> 2) * 64 + (mi & 3) * 16 + q * 4 + j;
                float v = acc[mi][ni][j] + bc;
                if (MODE == 1) {
                    // tanh-form GELU via fast exp (max dev vs erf-GELU ~3e-4)
                    float u = 1.5957691216057308f * (v + 0.044715f * v * v * v);
                    float s = 1.0f / (1.0f + __expf(-u));
                    outh[(size_t)row * N + col] = __float2bfloat16(v * s);
                } else {
                    outf[(size_t)row * N + col] =
                        x[(size_t)row * N + col] * g_res[row] + v * g_post[row];
                }
            }
        }
    }
}

// ---------------------------------------------------------------------------
// Workspace layout (~235.2 MB): W1T, W2T, Abuf, Hbuf, Wfold, gres, gpost
// ---------------------------------------------------------------------------
extern "C" void kernel_launch(void* const* d_in, const int* in_sizes, int n_in,
                              void* d_out, int out_size, void* d_ws, size_t ws_size,
                              hipStream_t stream) {
    const float* x          = (const float*)d_in[0];
    const float* phi_pre_w  = (const float*)d_in[1];
    const float* phi_pre_b  = (const float*)d_in[2];
    const float* phi_post_w = (const float*)d_in[3];
    const float* phi_post_b = (const float*)d_in[4];
    const float* phi_res_w  = (const float*)d_in[5];
    const float* phi_res_b  = (const float*)d_in[6];
    const float* alpha_pre  = (const float*)d_in[7];
    const float* alpha_post = (const float*)d_in[8];
    const float* alpha_res  = (const float*)d_in[9];
    const float* b_pre      = (const float*)d_in[10];
    const float* b_post     = (const float*)d_in[11];
    const float* b_res      = (const float*)d_in[12];
    const float* W1         = (const float*)d_in[13];
    const float* b1         = (const float*)d_in[14];
    const float* W2         = (const float*)d_in[15];
    const float* b2         = (const float*)d_in[16];
    float* out = (float*)d_out;

    char* ws = (char*)d_ws;
    __hip_bfloat16* W1T  = (__hip_bfloat16*)ws;                      // [DFF][DIM]
    __hip_bfloat16* W2T  = W1T + (size_t)DFF * DIM;                  // [DIM][DFF]
    __hip_bfloat16* Abuf = W2T + (size_t)DIM * DFF;                  // [NROWS][DIM]
    __hip_bfloat16* Hbuf = Abuf + (size_t)NROWS * DIM;               // [NROWS][DFF]
    float* Wfold = (float*)(Hbuf + (size_t)NROWS * DFF);             // [24][DIM]
    float* gres  = Wfold + NFOLD * DIM;
    float* gpost = gres + NROWS;

    fold_kernel<<<(NFOLD * DIM + 255) / 256, 256, 0, stream>>>(phi_pre_w, phi_post_w,
                                                               phi_res_w, Wfold);
    transpose_to_bf16<<<dim3(DFF / 32, DIM / 32), 256, 0, stream>>>(W1, W1T, DIM, DFF);
    transpose_to_bf16<<<dim3(DIM / 32, DFF / 32), 256, 0, stream>>>(W2, W2T, DFF, DIM);
    gating_kernel<<<NROWS / 8, 512, 0, stream>>>(x, Wfold, phi_pre_b, phi_post_b, phi_res_b,
                                                 alpha_pre, alpha_post, alpha_res,
                                                 b_pre, b_post, b_res, Abuf, gres, gpost);
    // GEMM1: [8192 x 2048] @ W1 -> gelu -> Hbuf [8192 x 8192]; grid 32x32=1024, NB=4
    gemm256<1, 4><<<1024, 512, 0, stream>>>(
        Abuf, W1T, NROWS, DFF, DIM, b1, Hbuf, nullptr, nullptr, nullptr, nullptr);
    // GEMM2: [8192 x 8192] @ W2 -> out [8192 x 2048]; grid 32x8=256, NB=1
    gemm256<2, 1><<<256, 512, 0, stream>>>(
        Hbuf, W2T, NROWS, DIM, DFF, b2, nullptr, out, x, gres, gpost);
}

// Round 21
// 627.974 us; speedup vs baseline: 1.0537x; 1.0020x over previous
//
#include <hip/hip_runtime.h>
#include <hip/hip_bf16.h>
#include <cstdint>
#include <cstddef>

// Problem constants (B=4, T=2048, DIM=2048, S=4, DFF=8192)
#define DIM   2048
#define DFF   8192
#define NROWS 8192   // B*T
#define NFOLD 24     // 4 (pre) + 4 (post) + 16 (res)

typedef float f32x4 __attribute__((ext_vector_type(4)));
typedef __bf16 bf16x8 __attribute__((ext_vector_type(8)));
typedef unsigned short u16x8 __attribute__((ext_vector_type(8)));

__device__ __forceinline__ float sigmoidf_(float v) { return 1.0f / (1.0f + expf(-v)); }

__device__ __forceinline__ unsigned short f2bf(float v) {
    union { __hip_bfloat16 h; unsigned short u; } cv;
    cv.h = __float2bfloat16(v);
    return cv.u;
}

__device__ __forceinline__ void async_copy16(const void* g, void* l) {
    __builtin_amdgcn_global_load_lds((const __attribute__((address_space(1))) void*)g,
                                     (__attribute__((address_space(3))) void*)l, 16, 0, 0);
}

// Raw workgroup barrier WITHOUT waitcnt drain (keeps global_load_lds in flight).
__device__ __forceinline__ void wg_barrier() {
    asm volatile("" ::: "memory");
    __builtin_amdgcn_s_barrier();
    asm volatile("" ::: "memory");
}

#define VM(n)  asm volatile("s_waitcnt vmcnt(" #n ")" ::: "memory")
#define LGKM0  asm volatile("s_waitcnt lgkmcnt(0)" ::: "memory")
// ROUND 21: r20 config (best, 629us) + 64x64-tile transpose with 16B loads
// AND 16B stores (was 32x32 with 8B stores). Bank-audited: both LDS phases
// <=2-way (free per m136); both global phases coalesced at 16B/lane.
// GEMMs/gating/fold untouched.

// ---------------------------------------------------------------------------
// Fold phi weights: Wfold[r][d] = sum_{j<4} src[r][j*DIM + d], r in [0,24)
// ---------------------------------------------------------------------------
__global__ __launch_bounds__(256) void fold_kernel(const float* __restrict__ pre_w,
                                                   const float* __restrict__ post_w,
                                                   const float* __restrict__ res_w,
                                                   float* __restrict__ Wfold) {
    int idx = blockIdx.x * 256 + threadIdx.x;
    if (idx >= NFOLD * DIM) return;
    int r = idx >> 11;          // /DIM
    int d = idx & (DIM - 1);
    const float* src;
    if (r < 4)      src = pre_w  + (size_t)r * (4 * DIM);
    else if (r < 8) src = post_w + (size_t)(r - 4) * (4 * DIM);
    else            src = res_w  + (size_t)(r - 8) * (4 * DIM);
    Wfold[idx] = src[d] + src[DIM + d] + src[2 * DIM + d] + src[3 * DIM + d];
}

// ---------------------------------------------------------------------------
// Transpose f32 [R][C] -> bf16 [C][R]. 64x64 tile, 256 threads.
// Load: 4x float4/thread (16B). Store: 2x ushort8/thread (16B).
// Bank audit: load bank=(r+4c+k)&31 -> 2-way; store-read bank=
// (8(t&7)+(t>>3)+j)&31 -> exactly 2-way. Both free (m136).
// ---------------------------------------------------------------------------
__global__ __launch_bounds__(256) void transpose_to_bf16(const float* __restrict__ in,
                                                         __hip_bfloat16* __restrict__ out,
                                                         int R, int C) {
    __shared__ float tile[64][65];
    const int bx = blockIdx.x, by = blockIdx.y;
    const int t = threadIdx.x;

    {
        const int col4 = (t & 15) * 4;
#pragma unroll
        for (int i = 0; i < 4; ++i) {
            const int r = (t >> 4) + i * 16;
            float4 v = *(const float4*)(in + (size_t)(by * 64 + r) * C + bx * 64 + col4);
            tile[r][col4 + 0] = v.x; tile[r][col4 + 1] = v.y;
            tile[r][col4 + 2] = v.z; tile[r][col4 + 3] = v.w;
        }
    }
    __syncthreads();
    {
        const int or8 = (t & 7) * 8;
#pragma unroll
        for (int i = 0; i < 2; ++i) {
            const int oc = (t >> 3) + i * 32;
            u16x8 u;
#pragma unroll
            for (int j = 0; j < 8; ++j) u[j] = f2bf(tile[or8 + j][oc]);
            *reinterpret_cast<u16x8*>(out + (size_t)(bx * 64 + oc) * R + by * 64 + or8) = u;
        }
    }
}

// ---------------------------------------------------------------------------
// Gating: wave-per-row, 8 rows per block (512 threads).
// ---------------------------------------------------------------------------
__global__ __launch_bounds__(512) void gating_kernel(
    const float* __restrict__ x, const float* __restrict__ Wfold,
    const float* __restrict__ phi_pre_b, const float* __restrict__ phi_post_b,
    const float* __restrict__ phi_res_b,
    const float* __restrict__ alpha_pre, const float* __restrict__ alpha_post,
    const float* __restrict__ alpha_res,
    const float* __restrict__ b_pre, const float* __restrict__ b_post,
    const float* __restrict__ b_res,
    __hip_bfloat16* __restrict__ Abuf,
    float* __restrict__ g_res_arr, float* __restrict__ g_post_arr) {
    const int tid = threadIdx.x;
    const int lane = tid & 63, wave = tid >> 6;
    const int row = blockIdx.x * 8 + wave;

    const float4* x4 = (const float4*)x + (size_t)row * 512;
    const float4* w4 = (const float4*)Wfold;

    float4 xv[8];
#pragma unroll
    for (int j = 0; j < 8; j++) xv[j] = x4[j * 64 + lane];

    float p[25];
    p[24] = 0.f;
#pragma unroll
    for (int j = 0; j < 8; j++)
        p[24] += xv[j].x * xv[j].x + xv[j].y * xv[j].y + xv[j].z * xv[j].z + xv[j].w * xv[j].w;

    for (int r = 0; r < NFOLD; r++) {
        float acc = 0.f;
#pragma unroll
        for (int j = 0; j < 8; j++) {
            float4 wv = w4[r * 512 + j * 64 + lane];
            acc += xv[j].x * wv.x + xv[j].y * wv.y + xv[j].z * wv.z + xv[j].w * wv.w;
        }
        p[r] = acc;
    }

#pragma unroll
    for (int r = 0; r < 25; r++) {
        float v = p[r];
#pragma unroll
        for (int off = 1; off < 64; off <<= 1) v += __shfl_xor(v, off, 64);
        p[r] = v;
    }

    const float rms = rsqrtf(p[24] / (float)DIM + 1.1920928955078125e-07f);
    const float ap = alpha_pre[0], aq = alpha_post[0], ar = alpha_res[0];
    float gpre = 0.f, gpost = 0.f;
#pragma unroll
    for (int s = 0; s < 4; s++) {
        gpre  += sigmoidf_(ap * (rms * p[s]     + phi_pre_b[s])  + b_pre[s]);
        gpost += 2.0f * sigmoidf_(aq * (rms * p[4 + s] + phi_post_b[s]) + b_post[s]);
    }
    float Mm[4][4];
#pragma unroll
    for (int i = 0; i < 4; i++)
#pragma unroll
        for (int j = 0; j < 4; j++) {
            int k = i * 4 + j;
            Mm[i][j] = expf(ar * (rms * p[8 + k] + phi_res_b[k]) + b_res[k]);
        }
    for (int it = 0; it < 10; ++it) {
#pragma unroll
        for (int i = 0; i < 4; i++) {
            float rs = 1.0f / (Mm[i][0] + Mm[i][1] + Mm[i][2] + Mm[i][3]);
#pragma unroll
            for (int j = 0; j < 4; j++) Mm[i][j] *= rs;
        }
#pragma unroll
        for (int j = 0; j < 4; j++) {
            float cs = 1.0f / (Mm[0][j] + Mm[1][j] + Mm[2][j] + Mm[3][j]);
#pragma unroll
            for (int i = 0; i < 4; i++) Mm[i][j] *= cs;
        }
    }
    float gres = 0.f;
#pragma unroll
    for (int i = 0; i < 4; i++)
#pragma unroll
        for (int j = 0; j < 4; j++) gres += Mm[i][j];

    __hip_bfloat16* arow = Abuf + (size_t)row * DIM;
#pragma unroll
    for (int j = 0; j < 8; j++) {
        ushort4 u;
        u.x = f2bf(xv[j].x * gpre); u.y = f2bf(xv[j].y * gpre);
        u.z = f2bf(xv[j].z * gpre); u.w = f2bf(xv[j].w * gpre);
        *reinterpret_cast<ushort4*>(arow + (j * 64 + lane) * 4) = u;
    }
    if (lane == 0) {
        g_res_arr[row]  = gres;
        g_post_arr[row] = gpost;
    }
}

// ---------------------------------------------------------------------------
// 256x256 bf16 GEMM — unit-ring, TWO barriers per K-tile (r17 winner).
//   C[M][N] = A[M][K] @ Bt[N][K]^T; 8 waves (2M x 4N); per-wave out 128x64;
//   BK=64; LDS 128 KiB = 2 parities x {A0,A1,B0,B1} 16 KB units.
// Units: A0: rows {0-63,128-191} [a0] | A1: rows {64-127,192-255} [a1]
//        B0: cols {0-31,64-95,128-159,192-223} [b0] | B1: +32 [b1]
// Unit region [128 rows][128 B], byte col ^ ((row&7)<<4); global_load_lds
// writes linearly, inverse XOR pre-applied on the per-lane global source.
//
// Phase = { rd; stg; [VM]; BAR; LGKM0; 32 MFMA }
//   Ph1: rd a0,b0,b1(t)[16]; stg A1(t+1),B1(t+1)
//   Ph2: rd a1(t)[8];        stg A0(t+2),B0(t+2); VM(4|0)
// WAR: LGKM0 < MFMA < next BAR (r16/r17-validated). vmcnt FIFO: steady
// entering Ph1(t): {A0,B0}(t+1)[4]; Ph1 +4 -> 8; Ph2 +4 -> 12; VM(4) keeps
// {A0,B0}(t+2), drains tile t+1. Prologue: t0{A0,B0,B1,A1}+{A0,B0}(1);
// VM(4). Tail: VM(0), stage macros self-guard.
// ---------------------------------------------------------------------------
#define RD_A(DST, REG)                                                            \
    _Pragma("unroll") for (int m = 0; m < 4; ++m) {                               \
        DST[m][0] = *(const bf16x8*)((REG) + baseA + m * 2048 + cb0);             \
        DST[m][1] = *(const bf16x8*)((REG) + baseA + m * 2048 + cb1);             \
    }
#define RD_B(DST, REG)                                                            \
    _Pragma("unroll") for (int n = 0; n < 2; ++n) {                               \
        DST[n][0] = *(const bf16x8*)((REG) + baseB + n * 2048 + cb0);             \
        DST[n][1] = *(const bf16x8*)((REG) + baseB + n * 2048 + cb1);             \
    }

#define MQ(AF, BF, MO, NO)                                                        \
    __builtin_amdgcn_s_setprio(1);                                                \
    _Pragma("unroll") for (int m = 0; m < 4; ++m)                                 \
    _Pragma("unroll") for (int n = 0; n < 2; ++n) {                               \
        acc[(MO) + m][(NO) + n] = __builtin_amdgcn_mfma_f32_16x16x32_bf16(        \
            AF[m][0], BF[n][0], acc[(MO) + m][(NO) + n], 0, 0, 0);                \
        acc[(MO) + m][(NO) + n] = __builtin_amdgcn_mfma_f32_16x16x32_bf16(        \
            AF[m][1], BF[n][1], acc[(MO) + m][(NO) + n], 0, 0, 0);                \
    }                                                                             \
    __builtin_amdgcn_s_setprio(0);

#define STG_A(t_, h_)                                                             \
    if ((t_) < nk) {                                                              \
        char* l_ = ldsA + (((t_) & 1) * 32768) + (h_) * 16384 + wave * 1024;      \
        async_copy16(Ab + aOff[0][h_] + (size_t)(t_) * 128, l_);                  \
        async_copy16(Ab + aOff[1][h_] + (size_t)(t_) * 128, l_ + 8192);           \
    }
#define STG_B(t_, h_)                                                             \
    if ((t_) < nk) {                                                              \
        char* l_ = ldsB + (((t_) & 1) * 32768) + (h_) * 16384 + wave * 1024;      \
        async_copy16(Bb + bOff[0][h_] + (size_t)(t_) * 128, l_);                  \
        async_copy16(Bb + bOff[1][h_] + (size_t)(t_) * 128, l_ + 8192);           \
    }

template <int MODE, int NB>
__global__ __launch_bounds__(512, 2) void gemm256(
    const __hip_bfloat16* __restrict__ A, const __hip_bfloat16* __restrict__ Bt,
    int M, int N, int K, const float* __restrict__ bias,
    __hip_bfloat16* __restrict__ outh, float* __restrict__ outf,
    const float* __restrict__ x, const float* __restrict__ g_res,
    const float* __restrict__ g_post) {
    __shared__ __align__(16) char ldsA[65536];
    __shared__ __align__(16) char ldsB[65536];

    // XCD band swizzle: each XCD owns an NB-wide column band of tiles.
    const int wg = blockIdx.x;
    const int xcd = wg & 7;
    const int i = wg >> 3;
    const int nt = xcd * NB + (i % NB);
    const int mt = i / NB;
    const int m0 = mt * 256;
    const int n0 = nt * 256;

    const int tid = threadIdx.x;
    const int lane = tid & 63;
    const int wave = tid >> 6;            // 0..7
    const int wr = wave >> 2;             // 0..1 (M)
    const int wc = wave & 3;              // 0..3 (N)
    const int q = lane >> 4;              // 0..3
    const int rr = lane & 7;

    // ds_read addressing (bytes within a 16 KB unit region)
    const uint32_t cb0 = (uint32_t)((q ^ rr) << 4);         // ks=0
    const uint32_t cb1 = (uint32_t)(((4 + q) ^ rr) << 4);   // ks=1
    const uint32_t baseA = (uint32_t)((wr * 64 + (lane & 15)) * 128);
    const uint32_t baseB = (uint32_t)((wc * 32 + (lane & 15)) * 128);

    // staging source addressing
    const uint32_t scb = (uint32_t)((((lane & 7) ^ ((lane >> 3) & 7))) << 4);
    const int lr = lane >> 3;             // 0..7
    const size_t K2 = (size_t)K * 2;
    size_t aOff[2][2], bOff[2][2];
#pragma unroll
    for (int ii = 0; ii < 2; ++ii)
#pragma unroll
        for (int h = 0; h < 2; ++h) {
            int gA = m0 + wave * 8 + lr + ii * 128 + h * 64;
            int gB = n0 + ((wave >> 2) + 2 * ii) * 64 + h * 32 + (wave & 3) * 8 + lr;
            aOff[ii][h] = (size_t)gA * K2 + scb;
            bOff[ii][h] = (size_t)gB * K2 + scb;
        }
    const char* Ab = (const char*)A;
    const char* Bb = (const char*)Bt;

    f32x4 acc[8][4];
#pragma unroll
    for (int m = 0; m < 8; ++m)
#pragma unroll
        for (int n = 0; n < 4; ++n) acc[m][n] = (f32x4){0.f, 0.f, 0.f, 0.f};

    const int nk = K / 64;

    // Prologue: tile0 {A0,B0,B1,A1} + {A0,B0}(1); VM(4) = tile0 landed,
    // {A0,B0}(1) in flight (the loop invariant).
    STG_A(0, 0); STG_B(0, 0); STG_B(0, 1); STG_A(0, 1);
    STG_A(1, 0); STG_B(1, 0);
    VM(4);
    wg_barrier();

    bf16x8 a0[4][2], a1[4][2];
    bf16x8 b0[2][2], b1[2][2];

    for (int kt = 0; kt < nk; ++kt) {
        const int c = kt & 1;
        const char* Ac = ldsA + c * 32768;
        const char* Bc = ldsB + c * 32768;
        // ---- Ph1: rd a0,b0,b1(t); stg A1(t+1),B1(t+1)
        RD_A(a0, Ac)
        RD_B(b0, Bc)
        RD_B(b1, Bc + 16384)
        STG_A(kt + 1, 1)
        STG_B(kt + 1, 1)
        wg_barrier();
        LGKM0;
        MQ(a0, b0, 0, 0)
        MQ(a0, b1, 0, 2)
        // ---- Ph2: rd a1(t); stg A0(t+2),B0(t+2); VM(4|0)
        RD_A(a1, Ac + 16384)
        STG_A(kt + 2, 0)
        STG_B(kt + 2, 0)
        if (kt + 2 < nk) { VM(4); } else { VM(0); }
        wg_barrier();
        LGKM0;
        MQ(a1, b0, 4, 0)
        MQ(a1, b1, 4, 2)
    }

    // Epilogue. Row/col mapping follows the interleaved unit layout:
    //   rows:  m0 + wr*128 + (mi>>2)*64 + (mi&3)*16 + q*4 + j
    //   cols:  n0 + wc*64  + (ni>>1)*32 + (ni&1)*16 + (lane&15)
#pragma unroll
    for (int mi = 0; mi < 8; ++mi) {
#pragma unroll
        for (int ni = 0; ni < 4; ++ni) {
            const int col = n0 + wc * 64 + (ni >> 1) * 32 + (ni & 1) * 16 + (lane & 15);
            const float bc = bias[col];
#pragma unroll
            for (int j = 0; j < 4; ++j) {
                const int row = m0 + wr * 128 + (mi >> 2) * 64 + (mi & 3) * 16 + q * 4 + j;
                float v = acc[mi][ni][j] + bc;
                if (MODE == 1) {
                    // tanh-form GELU via fast exp (max dev vs erf-GELU ~3e-4)
                    float u = 1.5957691216057308f * (v + 0.044715f * v * v * v);
                    float s = 1.0f / (1.0f + __expf(-u));
                    outh[(size_t)row * N + col] = __float2bfloat16(v * s);
                } else {
                    outf[(size_t)row * N + col] =
                        x[(size_t)row * N + col] * g_res[row] + v * g_post[row];
                }
            }
        }
    }
}

// ---------------------------------------------------------------------------
// Workspace layout (~235.2 MB): W1T, W2T, Abuf, Hbuf, Wfold, gres, gpost
// ---------------------------------------------------------------------------
extern "C" void kernel_launch(void* const* d_in, const int* in_sizes, int n_in,
                              void* d_out, int out_size, void* d_ws, size_t ws_size,
                              hipStream_t stream) {
    const float* x          = (const float*)d_in[0];
    const float* phi_pre_w  = (const float*)d_in[1];
    const float* phi_pre_b  = (const float*)d_in[2];
    const float* phi_post_w = (const float*)d_in[3];
    const float* phi_post_b = (const float*)d_in[4];
    const float* phi_res_w  = (const float*)d_in[5];
    const float* phi_res_b  = (const float*)d_in[6];
    const float* alpha_pre  = (const float*)d_in[7];
    const float* alpha_post = (const float*)d_in[8];
    const float* alpha_res  = (const float*)d_in[9];
    const float* b_pre      = (const float*)d_in[10];
    const float* b_post     = (const float*)d_in[11];
    const float* b_res      = (const float*)d_in[12];
    const float* W1         = (const float*)d_in[13];
    const float* b1         = (const float*)d_in[14];
    const float* W2         = (const float*)d_in[15];
    const float* b2         = (const float*)d_in[16];
    float* out = (float*)d_out;

    char* ws = (char*)d_ws;
    __hip_bfloat16* W1T  = (__hip_bfloat16*)ws;                      // [DFF][DIM]
    __hip_bfloat16* W2T  = W1T + (size_t)DFF * DIM;                  // [DIM][DFF]
    __hip_bfloat16* Abuf = W2T + (size_t)DIM * DFF;                  // [NROWS][DIM]
    __hip_bfloat16* Hbuf = Abuf + (size_t)NROWS * DIM;               // [NROWS][DFF]
    float* Wfold = (float*)(Hbuf + (size_t)NROWS * DFF);             // [24][DIM]
    float* gres  = Wfold + NFOLD * DIM;
    float* gpost = gres + NROWS;

    fold_kernel<<<(NFOLD * DIM + 255) / 256, 256, 0, stream>>>(phi_pre_w, phi_post_w,
                                                               phi_res_w, Wfold);
    transpose_to_bf16<<<dim3(DFF / 64, DIM / 64), 256, 0, stream>>>(W1, W1T, DIM, DFF);
    transpose_to_bf16<<<dim3(DIM / 64, DFF / 64), 256, 0, stream>>>(W2, W2T, DFF, DIM);
    gating_kernel<<<NROWS / 8, 512, 0, stream>>>(x, Wfold, phi_pre_b, phi_post_b, phi_res_b,
                                                 alpha_pre, alpha_post, alpha_res,
                                                 b_pre, b_post, b_res, Abuf, gres, gpost);
    // GEMM1: [8192 x 2048] @ W1 -> gelu -> Hbuf [8192 x 8192]; grid 32x32=1024, NB=4
    gemm256<1, 4><<<1024, 512, 0, stream>>>(
        Abuf, W1T, NROWS, DFF, DIM, b1, Hbuf, nullptr, nullptr, nullptr, nullptr);
    // GEMM2: [8192 x 8192] @ W2 -> out [8192 x 2048]; grid 32x8=256, NB=1
    gemm256<2, 1><<<256, 512, 0, stream>>>(
        Hbuf, W2T, NROWS, DIM, DFF, b2, nullptr, out, x, gres, gpost);
}